// Round 8
// baseline (192.749 us; speedup 1.0000x reference)
//
#include <hip/hip_runtime.h>
#include <hip/hip_bf16.h>

// RelationNet fused pipeline, fp32 in/out: k_prep + ONE persistent kernel.
// B=4 Q=256 S=128 C=256; feats 512 -> 256 -> 64 -> 1; BN (training) + ReLU each layer.
//
// Factorization: concat(uq,us)@W0^T = query@W0a^T + support@W0b^T => Aq[b,q,o], As[b,s,o]
// (b0 folded into As). BN0 stats analytic from per-b sums.
// GEMM0 ~fp32 via 3-term hi/lo bf16 split; GEMM1 z-side bf16-RNE, W1-side hi/lo split.
//
// R6 lesson: same-address atomic storms serialize (~150us). R7 lesson: __threadfence/
// acquire per block = buffer_wbl2/buffer_inv L2 storms (~30us per barrier).
// Now: cross-phase data written via AGENT-scope relaxed atomic stores (write-through to
// MALL, no dirty L2), readers first-touch (miss -> MALL). Barrier = syncthreads (drains
// vmcnt) + relaxed hierarchical counters. ZERO cache maintenance ops.

typedef __attribute__((ext_vector_type(4))) float f32x4;
typedef __attribute__((ext_vector_type(8))) short s16x8;

#define BN_EPS 1e-5f
#define INV_N  (1.0f/131072.0f)
#define NBLK   512

__device__ __forceinline__ unsigned pk_bf16(float a, float b) {
  float2 t; t.x = a; t.y = b;
  __hip_bfloat162 h = __float22bfloat162_rn(t);
  return *reinterpret_cast<unsigned*>(&h);
}
__device__ __forceinline__ void split2(float a, float b, unsigned& uh, unsigned& ul) {
  uh = pk_bf16(a, b);
  float ha = __uint_as_float(uh << 16);
  float hb = __uint_as_float(uh & 0xFFFF0000u);
  ul = pk_bf16(a - ha, b - hb);
}
__device__ __forceinline__ unsigned splitbf(float v) {
  unsigned u = __float_as_uint(v);
  unsigned hi = u >> 16;
  float r = v - __uint_as_float(u & 0xFFFF0000u);
  unsigned lo = __float_as_uint(r) >> 16;
  return (hi << 16) | lo;
}
// MALL-coherent (agent-scope) stores: no L2 dirty state, visible after vmcnt drain.
__device__ __forceinline__ void g_store(float* p, float v) {
  __hip_atomic_store(p, v, __ATOMIC_RELAXED, __HIP_MEMORY_SCOPE_AGENT);
}
__device__ __forceinline__ void g_store2(float* p, float v0, float v1) {
  union { unsigned long long u; float f[2]; } x; x.f[0] = v0; x.f[1] = v1;
  __hip_atomic_store((unsigned long long*)p, x.u, __ATOMIC_RELAXED, __HIP_MEMORY_SCOPE_AGENT);
}

union frag_u { s16x8 v; unsigned u[4]; };

struct Args {
  const float *Sf, *Qf, *W0, *b0, *g0, *bt0, *W1, *b1, *g1, *bt1, *W2, *b2, *g2, *bt2;
  float *Aq, *As, *y2, *ws0p, *ws1f, *ws2f, *out;
  ushort *W0h, *W0l, *W1h, *W1l;
  unsigned *bar;
};

// Fence-free grid barrier: __syncthreads drains each wave's vmcnt (compiler emits
// s_waitcnt vmcnt(0) before s_barrier), so all block stores (MALL-targeted) are
// globally visible. Then relaxed hierarchical counters: 64 groups of 8 -> root.
__device__ __forceinline__ void gridbar(unsigned* bar, int ph) {
  __syncthreads();
  if (threadIdx.x == 0) {
    unsigned* g = bar + ph * 80;   // [0..63] groups, [64] root
    __atomic_signal_fence(__ATOMIC_SEQ_CST);
    unsigned r = __hip_atomic_fetch_add(&g[blockIdx.x >> 3], 1u,
                                        __ATOMIC_RELAXED, __HIP_MEMORY_SCOPE_AGENT);
    if (r == 7)
      __hip_atomic_fetch_add(&g[64], 1u, __ATOMIC_RELAXED, __HIP_MEMORY_SCOPE_AGENT);
    while (__hip_atomic_load(&g[64], __ATOMIC_RELAXED, __HIP_MEMORY_SCOPE_AGENT) < 64u)
      __builtin_amdgcn_s_sleep(16);
    __atomic_signal_fence(__ATOMIC_SEQ_CST);
  }
  __syncthreads();
}

// Dispatch 1: split W0/W1 into hi/lo bf16; zero accumulators + barrier counters.
// (kernel-end implicit release flushes these to memory before k_all starts)
__global__ __launch_bounds__(256) void k_prep(
    const float* __restrict__ W0, const float* __restrict__ W1,
    ushort* __restrict__ W0h, ushort* __restrict__ W0l,
    ushort* __restrict__ W1h, ushort* __restrict__ W1l,
    float* __restrict__ ws0p, float* __restrict__ ws1f,
    float* __restrict__ ws2f, unsigned* __restrict__ bar)
{
  int bi = blockIdx.x, t = threadIdx.x;
  if (bi == 128) {
    for (int i = t; i < 4096; i += 256) ws0p[i] = 0.0f;
    for (int i = t; i < 1024; i += 256) ws1f[i] = 0.0f;
    if (t < 16) ws2f[t] = 0.0f;
    if (t < 240) bar[t] = 0u;
    return;
  }
#pragma unroll
  for (int k = 0; k < 4; k++) {
    int idx = bi * 1024 + k * 256 + t;
    unsigned p = splitbf(W0[idx]);
    W0h[idx] = (ushort)(p >> 16); W0l[idx] = (ushort)(p & 0xFFFFu);
  }
  if (bi >= 64) {
    int idx = (bi - 64) * 256 + t;
    unsigned q = splitbf(W1[idx]);
    W1h[idx] = (ushort)(q >> 16); W1l[idx] = (ushort)(q & 0xFFFFu);
  }
}

// Main-GEMM K-loop (layer-1): z0 generated in bf16-RNE A-frag layout in regs;
// y1 tile = z0 @ W1^T via MFMA (W1 hi/lo split, 2 MFMA/tile).
// Mapping: q = qt*16 + w*4 + mt; A-frag m(lane&15) = s-in-tile; k = channel.
// D: col(lane&15) = j, row(quad*4+r) = s-in-tile. Aq/As read with normal cached
// vector loads (first-touch after barrier -> L2 miss -> MALL -> fresh data).
__device__ __forceinline__ void mfma_kloop(
    const float* __restrict__ Aq, const float* __restrict__ As,
    const float* sh_a0c0, const ushort* __restrict__ W1h,
    const ushort* __restrict__ W1l,
    int b, int qt, int st, int w, int l15, int quad, f32x4 acc[4][4])
{
  const float* asrow = As + ((b << 7) + st * 16 + l15) * 256;
  const float* aqrow[4];
#pragma unroll
  for (int mt = 0; mt < 4; mt++)
    aqrow[mt] = Aq + ((b << 8) + qt * 16 + w * 4 + mt) * 256;

#pragma unroll
  for (int ko = 0; ko < 256; ko += 32) {
    int obase = ko + quad * 8;
    f32x4 a0v0 = *(const f32x4*)(sh_a0c0 + obase);
    f32x4 a0v1 = *(const f32x4*)(sh_a0c0 + obase + 4);
    f32x4 c0v0 = *(const f32x4*)(sh_a0c0 + 256 + obase);
    f32x4 c0v1 = *(const f32x4*)(sh_a0c0 + 256 + obase + 4);
    f32x4 as0 = *(const f32x4*)(asrow + obase);
    f32x4 as1 = *(const f32x4*)(asrow + obase + 4);

    s16x8 zh[4];
#pragma unroll
    for (int mt = 0; mt < 4; mt++) {
      f32x4 aq0 = *(const f32x4*)(aqrow[mt] + obase);
      f32x4 aq1 = *(const f32x4*)(aqrow[mt] + obase + 4);
      f32x4 z0 = (aq0 + as0) * a0v0 + c0v0;
      f32x4 z1 = (aq1 + as1) * a0v1 + c0v1;
      frag_u zz;
      zz.u[0] = pk_bf16(fmaxf(z0[0], 0.0f), fmaxf(z0[1], 0.0f));
      zz.u[1] = pk_bf16(fmaxf(z0[2], 0.0f), fmaxf(z0[3], 0.0f));
      zz.u[2] = pk_bf16(fmaxf(z1[0], 0.0f), fmaxf(z1[1], 0.0f));
      zz.u[3] = pk_bf16(fmaxf(z1[2], 0.0f), fmaxf(z1[3], 0.0f));
      zh[mt] = zz.v;
    }
#pragma unroll
    for (int nt = 0; nt < 4; nt++) {
      int off = (nt * 16 + l15) * 256 + obase;
      s16x8 bh = *(const s16x8*)(W1h + off);
      s16x8 bl = *(const s16x8*)(W1l + off);
#pragma unroll
      for (int mt = 0; mt < 4; mt++) {
        acc[mt][nt] = __builtin_amdgcn_mfma_f32_16x16x32_bf16(zh[mt], bh, acc[mt][nt], 0, 0, 0);
        acc[mt][nt] = __builtin_amdgcn_mfma_f32_16x16x32_bf16(zh[mt], bl, acc[mt][nt], 0, 0, 0);
      }
    }
  }
}

__global__ __launch_bounds__(256, 4) void k_all(Args a)
{
  int bi = blockIdx.x, t = threadIdx.x;
  int w = t >> 6, l = t & 63, l15 = l & 15, quad = l >> 4;

  __shared__ float sh_a0c0[512];
  __shared__ float red[2][4][4][16];
  __shared__ float sh_tot[128];
  __shared__ float sh_a1c1[128];
  __shared__ float rs[16], rs2[16];

  // ===== P1: gemm0 — Aq = Q@W0a^T ; As = S@W0b^T + b0. 384 wave-tiles, one per
  // block (wave 0 only) to spread across CUs. Aq/As stores are MALL-coherent.
  // ws0p: [0:1024) sumAq[b][o], [1024:2048) sumsqAq, [2048:3072) sumAs, [3072:4096) sumsqAs
  if (w == 0 && bi < 384) {
    int mtile = bi >> 2, ntile = bi & 3;
    bool isQ = (mtile < 64);
    const float* X; float* Out; int m0, koff, b;
    if (isQ) { m0 = mtile * 16; X = a.Qf; Out = a.Aq; koff = 0; b = m0 >> 8; }
    else     { m0 = (mtile - 64) * 16; X = a.Sf; Out = a.As; koff = 256; b = m0 >> 7; }
    int n0 = ntile * 64;

    f32x4 acc[4] = {};
#pragma unroll
    for (int ko = 0; ko < 256; ko += 32) {
      const float* row = X + (m0 + l15) * 256 + ko + quad * 8;
      f32x4 v0 = *(const f32x4*)(row);
      f32x4 v1 = *(const f32x4*)(row + 4);
      frag_u ah, al;
#pragma unroll
      for (int j = 0; j < 2; j++) {
        split2(v0[2 * j], v0[2 * j + 1], ah.u[j], al.u[j]);
        split2(v1[2 * j], v1[2 * j + 1], ah.u[2 + j], al.u[2 + j]);
      }
#pragma unroll
      for (int nt = 0; nt < 4; nt++) {
        int off = (n0 + nt * 16 + l15) * 512 + koff + ko + quad * 8;
        s16x8 bh = *(const s16x8*)(a.W0h + off);
        s16x8 bl = *(const s16x8*)(a.W0l + off);
        acc[nt] = __builtin_amdgcn_mfma_f32_16x16x32_bf16(ah.v, bh, acc[nt], 0, 0, 0);
        acc[nt] = __builtin_amdgcn_mfma_f32_16x16x32_bf16(al.v, bh, acc[nt], 0, 0, 0);
        acc[nt] = __builtin_amdgcn_mfma_f32_16x16x32_bf16(ah.v, bl, acc[nt], 0, 0, 0);
      }
    }
#pragma unroll
    for (int nt = 0; nt < 4; nt++) {
      int o = n0 + nt * 16 + l15;
      float bias = isQ ? 0.0f : a.b0[o];
      float cs = 0, cs2 = 0;
#pragma unroll
      for (int r = 0; r < 4; r++) {
        float y = acc[nt][r] + bias;
        g_store(&Out[(m0 + quad * 4 + r) * 256 + o], y);
        cs += y; cs2 += y * y;
      }
      cs  += __shfl_xor(cs, 16);  cs  += __shfl_xor(cs, 32);
      cs2 += __shfl_xor(cs2, 16); cs2 += __shfl_xor(cs2, 32);
      if (quad == 0) {
        int base = isQ ? 0 : 2048;
        atomicAdd(&a.ws0p[base + b * 256 + o], cs);       // <=48 adds/address
        atomicAdd(&a.ws0p[base + 1024 + b * 256 + o], cs2);
      }
    }
  }
  gridbar(a.bar, 0);

  // ===== P2: BN0 finalize (redundant per block, first-touch ws0p) -> LDS;
  // one tile; BN1 partials -> 8-way-spread atomicAdd ws1f.
  {
    int o = t;
    float sumY = 0, cross = 0, SQ2 = 0, SS2 = 0;
#pragma unroll
    for (int b = 0; b < 4; b++) {
      float sq1 = a.ws0p[b * 256 + o];
      float ss1 = a.ws0p[2048 + b * 256 + o];
      SQ2 += a.ws0p[1024 + b * 256 + o];
      SS2 += a.ws0p[3072 + b * 256 + o];
      sumY += 128.0f * sq1 + 256.0f * ss1;
      cross += sq1 * ss1;
    }
    float mean = sumY * INV_N;
    float var = (128.0f * SQ2 + 256.0f * SS2 + 2.0f * cross) * INV_N - mean * mean;
    float aa = a.g0[o] * rsqrtf(var + BN_EPS);
    sh_a0c0[o] = aa;
    sh_a0c0[256 + o] = a.bt0[o] - mean * aa;
  }
  __syncthreads();

  int b_ = bi >> 7, rem = bi & 127, qt = rem >> 3, st = rem & 7;
  {
    f32x4 acc[4][4] = {};
    mfma_kloop(a.Aq, a.As, sh_a0c0, a.W1h, a.W1l, b_, qt, st, w, l15, quad, acc);

#pragma unroll
    for (int nt = 0; nt < 4; nt++) {
      float bias = a.b1[nt * 16 + l15];
      float s = 0, s2 = 0;
#pragma unroll
      for (int mt = 0; mt < 4; mt++)
#pragma unroll
        for (int r = 0; r < 4; r++) {
          float y = acc[mt][nt][r] + bias;
          s += y; s2 += y * y;
        }
      s  += __shfl_xor(s, 16);  s  += __shfl_xor(s, 32);
      s2 += __shfl_xor(s2, 16); s2 += __shfl_xor(s2, 32);
      if (quad == 0) { red[0][w][nt][l15] = s; red[1][w][nt][l15] = s2; }
    }
    __syncthreads();
    if (t < 128) {
      int which = t >> 6, j = t & 63, nt = j >> 4, jl = j & 15;
      float v = red[which][0][nt][jl] + red[which][1][nt][jl] +
                red[which][2][nt][jl] + red[which][3][nt][jl];
      atomicAdd(&a.ws1f[(bi & 7) * 128 + t], v);  // 64 adds/address
    }
  }
  gridbar(a.bar, 1);

  // ===== P3: BN1 finalize (redundant, reads 4KB ws1f first-touch); one tile;
  // y2 via MALL-coherent 8B stores; BN2 partials -> 8-way-spread atomicAdd.
  if (t < 128) {
    float accv = 0;
#pragma unroll
    for (int c = 0; c < 8; c++) accv += a.ws1f[c * 128 + t];
    sh_tot[t] = accv;
  }
  __syncthreads();
  if (t < 64) {
    float mean = sh_tot[t] * INV_N;
    float var = sh_tot[64 + t] * INV_N - mean * mean;
    float aa = a.g1[t] * rsqrtf(var + BN_EPS);
    sh_a1c1[t] = aa;
    sh_a1c1[64 + t] = a.bt1[t] - mean * aa;
  }
  __syncthreads();

  {
    f32x4 acc[4][4] = {};
    mfma_kloop(a.Aq, a.As, sh_a0c0, a.W1h, a.W1l, b_, qt, st, w, l15, quad, acc);

    float a1v[4], c1v[4], w2v[4], biasv[4];
#pragma unroll
    for (int nt = 0; nt < 4; nt++) {
      int j = nt * 16 + l15;
      a1v[nt] = sh_a1c1[j]; c1v[nt] = sh_a1c1[64 + j];
      w2v[nt] = a.W2[j]; biasv[nt] = a.b1[j];
    }
    float b2v = a.b2[0];
    float ls = 0, ls2 = 0;
#pragma unroll
    for (int mt = 0; mt < 4; mt++) {
      float part[4] = {0, 0, 0, 0};
#pragma unroll
      for (int nt = 0; nt < 4; nt++)
#pragma unroll
        for (int r = 0; r < 4; r++) {
          float y = acc[mt][nt][r] + biasv[nt];
          float z = fmaxf(a1v[nt] * y + c1v[nt], 0.0f);
          part[r] += z * w2v[nt];
        }
#pragma unroll
      for (int r = 0; r < 4; r++) {
        float p = part[r];
        p += __shfl_xor(p, 1); p += __shfl_xor(p, 2);
        p += __shfl_xor(p, 4); p += __shfl_xor(p, 8);
        part[r] = p + b2v;
      }
      if (l15 == 0) {
        int q = qt * 16 + w * 4 + mt;
        int P = ((b_ * 256 + q) * 128) + st * 16 + quad * 4;
        g_store2(&a.y2[P], part[0], part[1]);
        g_store2(&a.y2[P + 2], part[2], part[3]);
#pragma unroll
        for (int r = 0; r < 4; r++) { ls += part[r]; ls2 += part[r] * part[r]; }
      }
    }
    if (l15 == 0) { rs[t >> 4] = ls; rs2[t >> 4] = ls2; }
    __syncthreads();
    if (t == 0) {
      float s = 0, s2 = 0;
#pragma unroll
      for (int i = 0; i < 16; i++) { s += rs[i]; s2 += rs2[i]; }
      atomicAdd(&a.ws2f[(bi & 7) * 2], s);       // 64 adds/address
      atomicAdd(&a.ws2f[(bi & 7) * 2 + 1], s2);
    }
  }
  gridbar(a.bar, 2);

  // ===== P4: BN2 finalize (redundant, 16 floats first-touch); out, 1 float/thread
  {
    float s = 0, s2 = 0;
#pragma unroll
    for (int c = 0; c < 8; c++) { s += a.ws2f[c * 2]; s2 += a.ws2f[c * 2 + 1]; }
    float mean = s * INV_N;
    float var = s2 * INV_N - mean * mean;
    float aa = a.g2[0] * rsqrtf(var + BN_EPS);
    float cc = a.bt2[0] - mean * aa;
    int gtid = bi * 256 + t;           // 512*256 = 131072 exactly
    float v = a.y2[gtid];              // first-touch -> MALL -> fresh
    a.out[gtid] = fmaxf(aa * v + cc, 0.0f);
  }
}

extern "C" void kernel_launch(void* const* d_in, const int* in_sizes, int n_in,
                              void* d_out, int out_size, void* d_ws, size_t ws_size,
                              hipStream_t stream)
{
  float* ws = (float*)d_ws;
  Args a;
  a.Sf  = (const float*)d_in[0];   // support [4,128,256]
  a.Qf  = (const float*)d_in[1];   // query   [4,256,256]
  a.W0  = (const float*)d_in[2];   // [256,512]
  a.b0  = (const float*)d_in[3];
  a.g0  = (const float*)d_in[4];
  a.bt0 = (const float*)d_in[5];
  a.W1  = (const float*)d_in[6];   // [64,256]
  a.b1  = (const float*)d_in[7];
  a.g1  = (const float*)d_in[8];
  a.bt1 = (const float*)d_in[9];
  a.W2  = (const float*)d_in[10];  // [1,64]
  a.b2  = (const float*)d_in[11];
  a.g2  = (const float*)d_in[12];
  a.bt2 = (const float*)d_in[13];

  a.Aq   = ws;                       // 262144 f
  a.As   = ws + 262144;              // 131072 f
  a.y2   = ws + 393216;              // 131072 f
  a.ws0p = ws + 524288;              // 4096 f (atomic accum)
  a.ws1f = ws + 528384;              // 8*128 = 1024 f (spread atomic accum)
  a.ws2f = ws + 529408;              // 16 f
  a.bar  = (unsigned*)(ws + 529424); // 240 u32 (3 phases x 80)
  a.W0h  = (ushort*)(ws + 529664);   // 131072 u16 = 65536 f
  a.W0l  = (ushort*)(ws + 595200);   // 131072 u16
  a.W1h  = (ushort*)(ws + 660736);   // 16384 u16 = 8192 f
  a.W1l  = (ushort*)(ws + 668928);   // 16384 u16 -> total ~2.7 MB
  a.out  = (float*)d_out;

  k_prep<<<129, 256, 0, stream>>>(a.W0, a.W1, a.W0h, a.W0l, a.W1h, a.W1l,
                                  a.ws0p, a.ws1f, a.ws2f, a.bar);
  k_all<<<NBLK, 256, 0, stream>>>(a);
}

// Round 9
// 176.642 us; speedup vs baseline: 1.0912x; 1.0912x over previous
//
#include <hip/hip_runtime.h>
#include <hip/hip_bf16.h>

// RelationNet fused pipeline, fp32 in/out: k_prep + ONE persistent kernel.
// B=4 Q=256 S=128 C=256; feats 512 -> 256 -> 64 -> 1; BN (training) + ReLU each layer.
//
// Factorization: concat(uq,us)@W0^T = query@W0a^T + support@W0b^T => Aq[b,q,o], As[b,s,o]
// (b0 folded into As). BN0 stats analytic from per-b sums.
// GEMM0 ~fp32 via 3-term hi/lo bf16 split; GEMM1 z-side bf16-RNE, W1-side hi/lo split.
//
// Barrier history: R6 same-address atomic storms (~150us). R7 fences (no effect).
// R8 fence-free, still ~35us/barrier. Diagnosis: POLLING with relaxed agent atomic
// LOAD caches a stale counter line in the local (non-coherent) XCD L2 and spins on
// it until random eviction. Fix: poll with atomic RMW fetch_add(0) — RMWs execute
// at the MALL coherence point (m20: cross-XCD atomicAdd verified). Release flags are
// per-group and cache-line-spaced (8 pollers/address).

typedef __attribute__((ext_vector_type(4))) float f32x4;
typedef __attribute__((ext_vector_type(8))) short s16x8;

#define BN_EPS 1e-5f
#define INV_N  (1.0f/131072.0f)
#define NBLK   512

__device__ __forceinline__ unsigned pk_bf16(float a, float b) {
  float2 t; t.x = a; t.y = b;
  __hip_bfloat162 h = __float22bfloat162_rn(t);
  return *reinterpret_cast<unsigned*>(&h);
}
__device__ __forceinline__ void split2(float a, float b, unsigned& uh, unsigned& ul) {
  uh = pk_bf16(a, b);
  float ha = __uint_as_float(uh << 16);
  float hb = __uint_as_float(uh & 0xFFFF0000u);
  ul = pk_bf16(a - ha, b - hb);
}
__device__ __forceinline__ unsigned splitbf(float v) {
  unsigned u = __float_as_uint(v);
  unsigned hi = u >> 16;
  float r = v - __uint_as_float(u & 0xFFFF0000u);
  unsigned lo = __float_as_uint(r) >> 16;
  return (hi << 16) | lo;
}
// MALL-coherent (agent-scope) stores: bypass dirty-L2 state; visible after vmcnt drain.
// (Correctness of this path is proven by R7/R8 passing with cross-XCD readers.)
__device__ __forceinline__ void g_store(float* p, float v) {
  __hip_atomic_store(p, v, __ATOMIC_RELAXED, __HIP_MEMORY_SCOPE_AGENT);
}
__device__ __forceinline__ void g_store2(float* p, float v0, float v1) {
  union { unsigned long long u; float f[2]; } x; x.f[0] = v0; x.f[1] = v1;
  __hip_atomic_store((unsigned long long*)p, x.u, __ATOMIC_RELAXED, __HIP_MEMORY_SCOPE_AGENT);
}

union frag_u { s16x8 v; unsigned u[4]; };

struct Args {
  const float *Sf, *Qf, *W0, *b0, *g0, *bt0, *W1, *b1, *g1, *bt1, *W2, *b2, *g2, *bt2;
  float *Aq, *As, *y2, *ws0p, *ws1f, *ws2f, *out;
  ushort *W0h, *W0l, *W1h, *W1l;
  unsigned *bar;
};

// Grid barrier, RMW-polled. Per phase: [0..63] group counters, [64] root,
// [128 + g*16] release flags (one 64B line per group, 8 polling blocks each).
// __syncthreads drains vmcnt (all agent stores globally visible before arrive).
__device__ __forceinline__ void gridbar(unsigned* bar, int ph) {
  __syncthreads();
  if (threadIdx.x == 0) {
    unsigned* base = bar + ph * 1152;
    unsigned g = blockIdx.x >> 3;
    unsigned* flag = base + 128 + g * 16;
    unsigned r = __hip_atomic_fetch_add(&base[g], 1u, __ATOMIC_RELAXED, __HIP_MEMORY_SCOPE_AGENT);
    if (r == 7) {
      unsigned q = __hip_atomic_fetch_add(&base[64], 1u, __ATOMIC_RELAXED, __HIP_MEMORY_SCOPE_AGENT);
      if (q == 63) {  // last group in: broadcast release
        for (int i = 0; i < 64; i++)
          __hip_atomic_store(base + 128 + i * 16, 1u, __ATOMIC_RELAXED, __HIP_MEMORY_SCOPE_AGENT);
      }
    }
    while (__hip_atomic_fetch_add(flag, 0u, __ATOMIC_RELAXED, __HIP_MEMORY_SCOPE_AGENT) == 0u)
      __builtin_amdgcn_s_sleep(4);
  }
  __syncthreads();
}

// Dispatch 1: split W0/W1 into hi/lo bf16; zero accumulators + barrier state.
__global__ __launch_bounds__(256) void k_prep(
    const float* __restrict__ W0, const float* __restrict__ W1,
    ushort* __restrict__ W0h, ushort* __restrict__ W0l,
    ushort* __restrict__ W1h, ushort* __restrict__ W1l,
    float* __restrict__ ws0p, float* __restrict__ ws1f,
    float* __restrict__ ws2f, unsigned* __restrict__ bar)
{
  int bi = blockIdx.x, t = threadIdx.x;
  if (bi == 128) {
    for (int i = t; i < 4096; i += 256) ws0p[i] = 0.0f;
    for (int i = t; i < 1024; i += 256) ws1f[i] = 0.0f;
    if (t < 16) ws2f[t] = 0.0f;
    for (int i = t; i < 3456; i += 256) bar[i] = 0u;
    return;
  }
#pragma unroll
  for (int k = 0; k < 4; k++) {
    int idx = bi * 1024 + k * 256 + t;
    unsigned p = splitbf(W0[idx]);
    W0h[idx] = (ushort)(p >> 16); W0l[idx] = (ushort)(p & 0xFFFFu);
  }
  if (bi >= 64) {
    int idx = (bi - 64) * 256 + t;
    unsigned q = splitbf(W1[idx]);
    W1h[idx] = (ushort)(q >> 16); W1l[idx] = (ushort)(q & 0xFFFFu);
  }
}

// Main-GEMM K-loop (layer-1): z0 generated in bf16-RNE A-frag layout in regs;
// y1 tile = z0 @ W1^T via MFMA (W1 hi/lo split, 2 MFMA/tile).
// Mapping: q = qt*16 + w*4 + mt; A-frag m(lane&15) = s-in-tile; k = channel.
// D: col(lane&15) = j, row(quad*4+r) = s-in-tile. Aq/As read with normal cached
// loads (no local-L2 copy exists: they were written via L2-bypassing stores).
__device__ __forceinline__ void mfma_kloop(
    const float* __restrict__ Aq, const float* __restrict__ As,
    const float* sh_a0c0, const ushort* __restrict__ W1h,
    const ushort* __restrict__ W1l,
    int b, int qt, int st, int w, int l15, int quad, f32x4 acc[4][4])
{
  const float* asrow = As + ((b << 7) + st * 16 + l15) * 256;
  const float* aqrow[4];
#pragma unroll
  for (int mt = 0; mt < 4; mt++)
    aqrow[mt] = Aq + ((b << 8) + qt * 16 + w * 4 + mt) * 256;

#pragma unroll
  for (int ko = 0; ko < 256; ko += 32) {
    int obase = ko + quad * 8;
    f32x4 a0v0 = *(const f32x4*)(sh_a0c0 + obase);
    f32x4 a0v1 = *(const f32x4*)(sh_a0c0 + obase + 4);
    f32x4 c0v0 = *(const f32x4*)(sh_a0c0 + 256 + obase);
    f32x4 c0v1 = *(const f32x4*)(sh_a0c0 + 256 + obase + 4);
    f32x4 as0 = *(const f32x4*)(asrow + obase);
    f32x4 as1 = *(const f32x4*)(asrow + obase + 4);

    s16x8 zh[4];
#pragma unroll
    for (int mt = 0; mt < 4; mt++) {
      f32x4 aq0 = *(const f32x4*)(aqrow[mt] + obase);
      f32x4 aq1 = *(const f32x4*)(aqrow[mt] + obase + 4);
      f32x4 z0 = (aq0 + as0) * a0v0 + c0v0;
      f32x4 z1 = (aq1 + as1) * a0v1 + c0v1;
      frag_u zz;
      zz.u[0] = pk_bf16(fmaxf(z0[0], 0.0f), fmaxf(z0[1], 0.0f));
      zz.u[1] = pk_bf16(fmaxf(z0[2], 0.0f), fmaxf(z0[3], 0.0f));
      zz.u[2] = pk_bf16(fmaxf(z1[0], 0.0f), fmaxf(z1[1], 0.0f));
      zz.u[3] = pk_bf16(fmaxf(z1[2], 0.0f), fmaxf(z1[3], 0.0f));
      zh[mt] = zz.v;
    }
#pragma unroll
    for (int nt = 0; nt < 4; nt++) {
      int off = (nt * 16 + l15) * 256 + obase;
      s16x8 bh = *(const s16x8*)(W1h + off);
      s16x8 bl = *(const s16x8*)(W1l + off);
#pragma unroll
      for (int mt = 0; mt < 4; mt++) {
        acc[mt][nt] = __builtin_amdgcn_mfma_f32_16x16x32_bf16(zh[mt], bh, acc[mt][nt], 0, 0, 0);
        acc[mt][nt] = __builtin_amdgcn_mfma_f32_16x16x32_bf16(zh[mt], bl, acc[mt][nt], 0, 0, 0);
      }
    }
  }
}

__global__ __launch_bounds__(256, 4) void k_all(Args a)
{
  int bi = blockIdx.x, t = threadIdx.x;
  int w = t >> 6, l = t & 63, l15 = l & 15, quad = l >> 4;

  __shared__ float sh_a0c0[512];
  __shared__ float red[2][4][4][16];
  __shared__ float sh_tot[128];
  __shared__ float sh_a1c1[128];
  __shared__ float rs[16], rs2[16];

  // ===== P1: gemm0 — Aq = Q@W0a^T ; As = S@W0b^T + b0. 384 wave-tiles, wave 0
  // of blocks 0..383. Aq/As via MALL-coherent stores.
  // ws0p: [0:1024) sumAq[b][o], [1024:2048) sumsqAq, [2048:3072) sumAs, [3072:4096) sumsqAs
  if (w == 0 && bi < 384) {
    int mtile = bi >> 2, ntile = bi & 3;
    bool isQ = (mtile < 64);
    const float* X; float* Out; int m0, koff, b;
    if (isQ) { m0 = mtile * 16; X = a.Qf; Out = a.Aq; koff = 0; b = m0 >> 8; }
    else     { m0 = (mtile - 64) * 16; X = a.Sf; Out = a.As; koff = 256; b = m0 >> 7; }
    int n0 = ntile * 64;

    f32x4 acc[4] = {};
#pragma unroll
    for (int ko = 0; ko < 256; ko += 32) {
      const float* row = X + (m0 + l15) * 256 + ko + quad * 8;
      f32x4 v0 = *(const f32x4*)(row);
      f32x4 v1 = *(const f32x4*)(row + 4);
      frag_u ah, al;
#pragma unroll
      for (int j = 0; j < 2; j++) {
        split2(v0[2 * j], v0[2 * j + 1], ah.u[j], al.u[j]);
        split2(v1[2 * j], v1[2 * j + 1], ah.u[2 + j], al.u[2 + j]);
      }
#pragma unroll
      for (int nt = 0; nt < 4; nt++) {
        int off = (n0 + nt * 16 + l15) * 512 + koff + ko + quad * 8;
        s16x8 bh = *(const s16x8*)(a.W0h + off);
        s16x8 bl = *(const s16x8*)(a.W0l + off);
        acc[nt] = __builtin_amdgcn_mfma_f32_16x16x32_bf16(ah.v, bh, acc[nt], 0, 0, 0);
        acc[nt] = __builtin_amdgcn_mfma_f32_16x16x32_bf16(al.v, bh, acc[nt], 0, 0, 0);
        acc[nt] = __builtin_amdgcn_mfma_f32_16x16x32_bf16(ah.v, bl, acc[nt], 0, 0, 0);
      }
    }
#pragma unroll
    for (int nt = 0; nt < 4; nt++) {
      int o = n0 + nt * 16 + l15;
      float bias = isQ ? 0.0f : a.b0[o];
      float cs = 0, cs2 = 0;
#pragma unroll
      for (int r = 0; r < 4; r++) {
        float y = acc[nt][r] + bias;
        g_store(&Out[(m0 + quad * 4 + r) * 256 + o], y);
        cs += y; cs2 += y * y;
      }
      cs  += __shfl_xor(cs, 16);  cs  += __shfl_xor(cs, 32);
      cs2 += __shfl_xor(cs2, 16); cs2 += __shfl_xor(cs2, 32);
      if (quad == 0) {
        int base = isQ ? 0 : 2048;
        atomicAdd(&a.ws0p[base + b * 256 + o], cs);       // <=48 adds/address
        atomicAdd(&a.ws0p[base + 1024 + b * 256 + o], cs2);
      }
    }
  }
  gridbar(a.bar, 0);

  // ===== P2: BN0 finalize (redundant per block) -> LDS; one tile; BN1 partials
  // -> 8-way-spread atomicAdd ws1f (64 adds/address).
  {
    int o = t;
    float sumY = 0, cross = 0, SQ2 = 0, SS2 = 0;
#pragma unroll
    for (int b = 0; b < 4; b++) {
      float sq1 = a.ws0p[b * 256 + o];
      float ss1 = a.ws0p[2048 + b * 256 + o];
      SQ2 += a.ws0p[1024 + b * 256 + o];
      SS2 += a.ws0p[3072 + b * 256 + o];
      sumY += 128.0f * sq1 + 256.0f * ss1;
      cross += sq1 * ss1;
    }
    float mean = sumY * INV_N;
    float var = (128.0f * SQ2 + 256.0f * SS2 + 2.0f * cross) * INV_N - mean * mean;
    float aa = a.g0[o] * rsqrtf(var + BN_EPS);
    sh_a0c0[o] = aa;
    sh_a0c0[256 + o] = a.bt0[o] - mean * aa;
  }
  __syncthreads();

  int b_ = bi >> 7, rem = bi & 127, qt = rem >> 3, st = rem & 7;
  {
    f32x4 acc[4][4] = {};
    mfma_kloop(a.Aq, a.As, sh_a0c0, a.W1h, a.W1l, b_, qt, st, w, l15, quad, acc);

#pragma unroll
    for (int nt = 0; nt < 4; nt++) {
      float bias = a.b1[nt * 16 + l15];
      float s = 0, s2 = 0;
#pragma unroll
      for (int mt = 0; mt < 4; mt++)
#pragma unroll
        for (int r = 0; r < 4; r++) {
          float y = acc[mt][nt][r] + bias;
          s += y; s2 += y * y;
        }
      s  += __shfl_xor(s, 16);  s  += __shfl_xor(s, 32);
      s2 += __shfl_xor(s2, 16); s2 += __shfl_xor(s2, 32);
      if (quad == 0) { red[0][w][nt][l15] = s; red[1][w][nt][l15] = s2; }
    }
    __syncthreads();
    if (t < 128) {
      int which = t >> 6, j = t & 63, nt = j >> 4, jl = j & 15;
      float v = red[which][0][nt][jl] + red[which][1][nt][jl] +
                red[which][2][nt][jl] + red[which][3][nt][jl];
      atomicAdd(&a.ws1f[(bi & 7) * 128 + t], v);
    }
  }
  gridbar(a.bar, 1);

  // ===== P3: BN1 finalize (redundant); one tile; y2 via MALL stores; BN2
  // partials -> 8-way-spread atomicAdd ws2f.
  if (t < 128) {
    float accv = 0;
#pragma unroll
    for (int c = 0; c < 8; c++) accv += a.ws1f[c * 128 + t];
    sh_tot[t] = accv;
  }
  __syncthreads();
  if (t < 64) {
    float mean = sh_tot[t] * INV_N;
    float var = sh_tot[64 + t] * INV_N - mean * mean;
    float aa = a.g1[t] * rsqrtf(var + BN_EPS);
    sh_a1c1[t] = aa;
    sh_a1c1[64 + t] = a.bt1[t] - mean * aa;
  }
  __syncthreads();

  {
    f32x4 acc[4][4] = {};
    mfma_kloop(a.Aq, a.As, sh_a0c0, a.W1h, a.W1l, b_, qt, st, w, l15, quad, acc);

    float a1v[4], c1v[4], w2v[4], biasv[4];
#pragma unroll
    for (int nt = 0; nt < 4; nt++) {
      int j = nt * 16 + l15;
      a1v[nt] = sh_a1c1[j]; c1v[nt] = sh_a1c1[64 + j];
      w2v[nt] = a.W2[j]; biasv[nt] = a.b1[j];
    }
    float b2v = a.b2[0];
    float ls = 0, ls2 = 0;
#pragma unroll
    for (int mt = 0; mt < 4; mt++) {
      float part[4] = {0, 0, 0, 0};
#pragma unroll
      for (int nt = 0; nt < 4; nt++)
#pragma unroll
        for (int r = 0; r < 4; r++) {
          float y = acc[mt][nt][r] + biasv[nt];
          float z = fmaxf(a1v[nt] * y + c1v[nt], 0.0f);
          part[r] += z * w2v[nt];
        }
#pragma unroll
      for (int r = 0; r < 4; r++) {
        float p = part[r];
        p += __shfl_xor(p, 1); p += __shfl_xor(p, 2);
        p += __shfl_xor(p, 4); p += __shfl_xor(p, 8);
        part[r] = p + b2v;
      }
      if (l15 == 0) {
        int q = qt * 16 + w * 4 + mt;
        int P = ((b_ * 256 + q) * 128) + st * 16 + quad * 4;
        g_store2(&a.y2[P], part[0], part[1]);
        g_store2(&a.y2[P + 2], part[2], part[3]);
#pragma unroll
        for (int r = 0; r < 4; r++) { ls += part[r]; ls2 += part[r] * part[r]; }
      }
    }
    if (l15 == 0) { rs[t >> 4] = ls; rs2[t >> 4] = ls2; }
    __syncthreads();
    if (t == 0) {
      float s = 0, s2 = 0;
#pragma unroll
      for (int i = 0; i < 16; i++) { s += rs[i]; s2 += rs2[i]; }
      atomicAdd(&a.ws2f[(bi & 7) * 2], s);
      atomicAdd(&a.ws2f[(bi & 7) * 2 + 1], s2);
    }
  }
  gridbar(a.bar, 2);

  // ===== P4: BN2 finalize (redundant, 16 floats); out, 1 float/thread
  {
    float s = 0, s2 = 0;
#pragma unroll
    for (int c = 0; c < 8; c++) { s += a.ws2f[c * 2]; s2 += a.ws2f[c * 2 + 1]; }
    float mean = s * INV_N;
    float var = s2 * INV_N - mean * mean;
    float aa = a.g2[0] * rsqrtf(var + BN_EPS);
    float cc = a.bt2[0] - mean * aa;
    int gtid = bi * 256 + t;           // 512*256 = 131072 exactly
    float v = a.y2[gtid];
    a.out[gtid] = fmaxf(aa * v + cc, 0.0f);
  }
}

extern "C" void kernel_launch(void* const* d_in, const int* in_sizes, int n_in,
                              void* d_out, int out_size, void* d_ws, size_t ws_size,
                              hipStream_t stream)
{
  float* ws = (float*)d_ws;
  Args a;
  a.Sf  = (const float*)d_in[0];   // support [4,128,256]
  a.Qf  = (const float*)d_in[1];   // query   [4,256,256]
  a.W0  = (const float*)d_in[2];   // [256,512]
  a.b0  = (const float*)d_in[3];
  a.g0  = (const float*)d_in[4];
  a.bt0 = (const float*)d_in[5];
  a.W1  = (const float*)d_in[6];   // [64,256]
  a.b1  = (const float*)d_in[7];
  a.g1  = (const float*)d_in[8];
  a.bt1 = (const float*)d_in[9];
  a.W2  = (const float*)d_in[10];  // [1,64]
  a.b2  = (const float*)d_in[11];
  a.g2  = (const float*)d_in[12];
  a.bt2 = (const float*)d_in[13];

  a.Aq   = ws;                       // 262144 f
  a.As   = ws + 262144;              // 131072 f
  a.y2   = ws + 393216;              // 131072 f
  a.ws0p = ws + 524288;              // 4096 f (atomic accum)
  a.ws1f = ws + 528384;              // 1024 f (8-way spread atomic accum)
  a.ws2f = ws + 529408;              // 16 f
  a.bar  = (unsigned*)(ws + 529424); // 3456 u32 (3 phases x 1152)
  a.W0h  = (ushort*)(ws + 532992);   // 131072 u16 = 65536 f
  a.W0l  = (ushort*)(ws + 598528);   // 131072 u16
  a.W1h  = (ushort*)(ws + 664064);   // 16384 u16 = 8192 f
  a.W1l  = (ushort*)(ws + 672256);   // 16384 u16 -> total ~2.7 MB
  a.out  = (float*)d_out;

  k_prep<<<129, 256, 0, stream>>>(a.W0, a.W1, a.W0h, a.W0l, a.W1h, a.W1l,
                                  a.ws0p, a.ws1f, a.ws2f, a.bar);
  k_all<<<NBLK, 256, 0, stream>>>(a);
}

// Round 10
// 160.850 us; speedup vs baseline: 1.1983x; 1.0982x over previous
//
#include <hip/hip_runtime.h>
#include <hip/hip_bf16.h>

// RelationNet fused pipeline, fp32 in/out — FOUR dispatches, no grid barriers.
// B=4 Q=256 S=128 C=256; feats 512 -> 256 -> 64 -> 1; BN (training) + ReLU each layer.
//
// Factorization: concat(uq,us)@W0^T = query@W0a^T + support@W0b^T => Aq[b,q,o], As[b,s,o]
// (b0 folded into As). BN0 stats analytic from per-b sums:
//   sum  y0 = S*sum(Aq) + Q*sum(As)
//   sum y0^2 = S*sum(Aq^2) + Q*sum(As^2) + 2*sum_b (sum_q Aq[b])·(sum_s As[b])
// GEMM0 ~fp32 via 3-term hi/lo bf16 split (in-register; fp32 weight load = same bytes
// as hi+lo bf16). GEMM1 z-side bf16-RNE, W1-side in-register hi/lo split.
//
// R5-R9 lesson: persistent kernel + grid barrier costs ~30us/phase on MI355X no matter
// the barrier mechanism (fences, relaxed loads, RMW polls all identical). Kernel
// boundaries are cheaper (~16us each). BN0: slot writes + redundant reduce (no zeroing
// needed). BN1/BN2: 8-way-spread atomicAdd (64 adds/addr), pads zeroed in D1.

typedef __attribute__((ext_vector_type(4))) float f32x4;
typedef __attribute__((ext_vector_type(8))) short s16x8;

#define BN_EPS 1e-5f
#define INV_N  (1.0f/131072.0f)

__device__ __forceinline__ unsigned pk_bf16(float a, float b) {
  float2 t; t.x = a; t.y = b;
  __hip_bfloat162 h = __float22bfloat162_rn(t);
  return *reinterpret_cast<unsigned*>(&h);
}
__device__ __forceinline__ void split2(float a, float b, unsigned& uh, unsigned& ul) {
  uh = pk_bf16(a, b);
  float ha = __uint_as_float(uh << 16);
  float hb = __uint_as_float(uh & 0xFFFF0000u);
  ul = pk_bf16(a - ha, b - hb);
}

union frag_u { s16x8 v; unsigned u[4]; };

struct Args {
  const float *Sf, *Qf, *W0, *b0, *g0, *bt0, *W1, *b1, *g1, *bt1, *W2, *b2, *g2, *bt2;
  float *Aq, *As, *y2, *ws0s, *ws1f, *ws2f, *out;
};

// ---------------------------------------------------------------------------
// D1: GEMM0. 97 blocks x 256 thr. Blocks 0..95: block bi = one 16-row chunk
// (mtile), wave w = one 16x64 tile (ntile=w). mtile<64: Aq (b=mtile>>4);
// else As chunk mt2=mtile-64 (b=mt2>>3), +b0 bias. W0 split in-register.
// BN0 partial slots (no atomics): ws0s[bi*512 + o] = sum over the block's 16
// rows of channel o; [bi*512+256+o] = sumsq. Block 96: zero ws1f/ws2f pads.
// ---------------------------------------------------------------------------
__global__ __launch_bounds__(256) void k_g0(Args a)
{
  int bi = blockIdx.x, t = threadIdx.x;
  if (bi == 96) {
    for (int i = t; i < 1024; i += 256) a.ws1f[i] = 0.0f;
    if (t < 16) a.ws2f[t] = 0.0f;
    return;
  }
  int w = t >> 6, l = t & 63, l15 = l & 15, quad = l >> 4;
  bool isQ = (bi < 64);
  const float* X; float* Out; int m0, koff;
  if (isQ) { m0 = bi * 16; X = a.Qf; Out = a.Aq; koff = 0; }
  else     { m0 = (bi - 64) * 16; X = a.Sf; Out = a.As; koff = 256; }
  int n0 = w * 64;

  f32x4 acc[4] = {};
#pragma unroll
  for (int ko = 0; ko < 256; ko += 32) {
    const float* row = X + (m0 + l15) * 256 + ko + quad * 8;
    f32x4 v0 = *(const f32x4*)(row);
    f32x4 v1 = *(const f32x4*)(row + 4);
    frag_u ah, al;
#pragma unroll
    for (int j = 0; j < 2; j++) {
      split2(v0[2 * j], v0[2 * j + 1], ah.u[j], al.u[j]);
      split2(v1[2 * j], v1[2 * j + 1], ah.u[2 + j], al.u[2 + j]);
    }
#pragma unroll
    for (int nt = 0; nt < 4; nt++) {
      const float* wrow = a.W0 + (n0 + nt * 16 + l15) * 512 + koff + ko + quad * 8;
      f32x4 w0v = *(const f32x4*)(wrow);
      f32x4 w1v = *(const f32x4*)(wrow + 4);
      frag_u bh, bl;
      split2(w0v[0], w0v[1], bh.u[0], bl.u[0]);
      split2(w0v[2], w0v[3], bh.u[1], bl.u[1]);
      split2(w1v[0], w1v[1], bh.u[2], bl.u[2]);
      split2(w1v[2], w1v[3], bh.u[3], bl.u[3]);
      acc[nt] = __builtin_amdgcn_mfma_f32_16x16x32_bf16(ah.v, bh.v, acc[nt], 0, 0, 0);
      acc[nt] = __builtin_amdgcn_mfma_f32_16x16x32_bf16(al.v, bh.v, acc[nt], 0, 0, 0);
      acc[nt] = __builtin_amdgcn_mfma_f32_16x16x32_bf16(ah.v, bl.v, acc[nt], 0, 0, 0);
    }
  }
  // D: col = l15 (o-in-tile), row = quad*4 + r
#pragma unroll
  for (int nt = 0; nt < 4; nt++) {
    int o = n0 + nt * 16 + l15;
    float bias = isQ ? 0.0f : a.b0[o];
    float cs = 0, cs2 = 0;
#pragma unroll
    for (int r = 0; r < 4; r++) {
      float y = acc[nt][r] + bias;
      Out[(m0 + quad * 4 + r) * 256 + o] = y;
      cs += y; cs2 += y * y;
    }
    cs  += __shfl_xor(cs, 16);  cs  += __shfl_xor(cs, 32);
    cs2 += __shfl_xor(cs2, 16); cs2 += __shfl_xor(cs2, 32);
    if (quad == 0) {
      a.ws0s[bi * 512 + o] = cs;
      a.ws0s[bi * 512 + 256 + o] = cs2;
    }
  }
}

// ---------------------------------------------------------------------------
// Main-GEMM K-loop (layer-1): z0 generated in bf16-RNE A-frag layout in regs;
// y1 tile = z0 @ W1^T via MFMA, W1 split hi/lo in-register (2 MFMA per tile).
// Mapping: q = qt*16 + w*4 + mt; A-frag m(lane&15) = s-in-tile; k = channel.
// D: col(lane&15) = j, row(quad*4+r) = s-in-tile.
// ---------------------------------------------------------------------------
__device__ __forceinline__ void mfma_kloop(
    const float* __restrict__ Aq, const float* __restrict__ As,
    const float* sh_a0c0, const float* __restrict__ W1,
    int b, int qt, int st, int w, int l15, int quad, f32x4 acc[4][4])
{
  const float* asrow = As + ((b << 7) + st * 16 + l15) * 256;
  const float* aqrow[4];
#pragma unroll
  for (int mt = 0; mt < 4; mt++)
    aqrow[mt] = Aq + ((b << 8) + qt * 16 + w * 4 + mt) * 256;

#pragma unroll
  for (int ko = 0; ko < 256; ko += 32) {
    int obase = ko + quad * 8;
    f32x4 a0v0 = *(const f32x4*)(sh_a0c0 + obase);
    f32x4 a0v1 = *(const f32x4*)(sh_a0c0 + obase + 4);
    f32x4 c0v0 = *(const f32x4*)(sh_a0c0 + 256 + obase);
    f32x4 c0v1 = *(const f32x4*)(sh_a0c0 + 256 + obase + 4);
    f32x4 as0 = *(const f32x4*)(asrow + obase);
    f32x4 as1 = *(const f32x4*)(asrow + obase + 4);

    s16x8 zh[4];
#pragma unroll
    for (int mt = 0; mt < 4; mt++) {
      f32x4 aq0 = *(const f32x4*)(aqrow[mt] + obase);
      f32x4 aq1 = *(const f32x4*)(aqrow[mt] + obase + 4);
      f32x4 z0 = (aq0 + as0) * a0v0 + c0v0;
      f32x4 z1 = (aq1 + as1) * a0v1 + c0v1;
      frag_u zz;
      zz.u[0] = pk_bf16(fmaxf(z0[0], 0.0f), fmaxf(z0[1], 0.0f));
      zz.u[1] = pk_bf16(fmaxf(z0[2], 0.0f), fmaxf(z0[3], 0.0f));
      zz.u[2] = pk_bf16(fmaxf(z1[0], 0.0f), fmaxf(z1[1], 0.0f));
      zz.u[3] = pk_bf16(fmaxf(z1[2], 0.0f), fmaxf(z1[3], 0.0f));
      zh[mt] = zz.v;
    }
#pragma unroll
    for (int nt = 0; nt < 4; nt++) {
      const float* wrow = W1 + (nt * 16 + l15) * 256 + obase;
      f32x4 w0v = *(const f32x4*)(wrow);
      f32x4 w1v = *(const f32x4*)(wrow + 4);
      frag_u bh, bl;
      split2(w0v[0], w0v[1], bh.u[0], bl.u[0]);
      split2(w0v[2], w0v[3], bh.u[1], bl.u[1]);
      split2(w1v[0], w1v[1], bh.u[2], bl.u[2]);
      split2(w1v[2], w1v[3], bh.u[3], bl.u[3]);
#pragma unroll
      for (int mt = 0; mt < 4; mt++) {
        acc[mt][nt] = __builtin_amdgcn_mfma_f32_16x16x32_bf16(zh[mt], bh.v, acc[mt][nt], 0, 0, 0);
        acc[mt][nt] = __builtin_amdgcn_mfma_f32_16x16x32_bf16(zh[mt], bl.v, acc[mt][nt], 0, 0, 0);
      }
    }
  }
}

// Redundant per-block BN0 finalize from D1's slots -> LDS a0/c0.
__device__ __forceinline__ void bn0_finalize(const Args& a, int t, float* sh_a0c0)
{
  int o = t;
  float sumY = 0, cross = 0, SQ2 = 0, SS2 = 0;
#pragma unroll
  for (int b = 0; b < 4; b++) {
    float sq1 = 0, sq2 = 0, ss1 = 0, ss2 = 0;
#pragma unroll
    for (int c = 0; c < 16; c++) {
      sq1 += a.ws0s[(b * 16 + c) * 512 + o];
      sq2 += a.ws0s[(b * 16 + c) * 512 + 256 + o];
    }
#pragma unroll
    for (int c = 0; c < 8; c++) {
      ss1 += a.ws0s[(64 + b * 8 + c) * 512 + o];
      ss2 += a.ws0s[(64 + b * 8 + c) * 512 + 256 + o];
    }
    SQ2 += sq2; SS2 += ss2;
    sumY += 128.0f * sq1 + 256.0f * ss1;
    cross += sq1 * ss1;
  }
  float mean = sumY * INV_N;
  float var = (128.0f * SQ2 + 256.0f * SS2 + 2.0f * cross) * INV_N - mean * mean;
  float aa = a.g0[o] * rsqrtf(var + BN_EPS);
  sh_a0c0[o] = aa;
  sh_a0c0[256 + o] = a.bt0[o] - mean * aa;
}

// ---------------------------------------------------------------------------
// D2: main pass 1 — BN1 stats. 512 blocks, one (b,qt,st) tile each.
// BN1 partials -> 8-way-spread atomicAdd ws1f (64 adds/address).
// ---------------------------------------------------------------------------
__global__ __launch_bounds__(256) void k_m1(Args a)
{
  int bi = blockIdx.x, t = threadIdx.x;
  int w = t >> 6, l = t & 63, l15 = l & 15, quad = l >> 4;
  __shared__ float sh_a0c0[512];
  __shared__ float red[2][4][4][16];

  bn0_finalize(a, t, sh_a0c0);
  __syncthreads();

  int b_ = bi >> 7, rem = bi & 127, qt = rem >> 3, st = rem & 7;
  f32x4 acc[4][4] = {};
  mfma_kloop(a.Aq, a.As, sh_a0c0, a.W1, b_, qt, st, w, l15, quad, acc);

#pragma unroll
  for (int nt = 0; nt < 4; nt++) {
    float bias = a.b1[nt * 16 + l15];
    float s = 0, s2 = 0;
#pragma unroll
    for (int mt = 0; mt < 4; mt++)
#pragma unroll
      for (int r = 0; r < 4; r++) {
        float y = acc[mt][nt][r] + bias;
        s += y; s2 += y * y;
      }
    s  += __shfl_xor(s, 16);  s  += __shfl_xor(s, 32);
    s2 += __shfl_xor(s2, 16); s2 += __shfl_xor(s2, 32);
    if (quad == 0) { red[0][w][nt][l15] = s; red[1][w][nt][l15] = s2; }
  }
  __syncthreads();
  if (t < 128) {
    int which = t >> 6, j = t & 63, nt = j >> 4, jl = j & 15;
    float v = red[which][0][nt][jl] + red[which][1][nt][jl] +
              red[which][2][nt][jl] + red[which][3][nt][jl];
    atomicAdd(&a.ws1f[(bi & 7) * 128 + t], v);  // t<64: sum[j], t>=64: sumsq[j]
  }
}

// ---------------------------------------------------------------------------
// D3: main pass 2 — y2 + BN2 stats. 512 blocks, one tile each.
// ---------------------------------------------------------------------------
__global__ __launch_bounds__(256) void k_m2(Args a)
{
  int bi = blockIdx.x, t = threadIdx.x;
  int w = t >> 6, l = t & 63, l15 = l & 15, quad = l >> 4;
  __shared__ float sh_a0c0[512];
  __shared__ float sh_tot[128];
  __shared__ float sh_a1c1[128];
  __shared__ float rs[16], rs2[16];

  bn0_finalize(a, t, sh_a0c0);
  if (t < 128) {
    float accv = 0;
#pragma unroll
    for (int c = 0; c < 8; c++) accv += a.ws1f[c * 128 + t];
    sh_tot[t] = accv;
  }
  __syncthreads();
  if (t < 64) {
    float mean = sh_tot[t] * INV_N;
    float var = sh_tot[64 + t] * INV_N - mean * mean;
    float aa = a.g1[t] * rsqrtf(var + BN_EPS);
    sh_a1c1[t] = aa;
    sh_a1c1[64 + t] = a.bt1[t] - mean * aa;
  }
  __syncthreads();

  int b_ = bi >> 7, rem = bi & 127, qt = rem >> 3, st = rem & 7;
  f32x4 acc[4][4] = {};
  mfma_kloop(a.Aq, a.As, sh_a0c0, a.W1, b_, qt, st, w, l15, quad, acc);

  float a1v[4], c1v[4], w2v[4], biasv[4];
#pragma unroll
  for (int nt = 0; nt < 4; nt++) {
    int j = nt * 16 + l15;
    a1v[nt] = sh_a1c1[j]; c1v[nt] = sh_a1c1[64 + j];
    w2v[nt] = a.W2[j]; biasv[nt] = a.b1[j];
  }
  float b2v = a.b2[0];
  float ls = 0, ls2 = 0;
#pragma unroll
  for (int mt = 0; mt < 4; mt++) {
    float part[4] = {0, 0, 0, 0};
#pragma unroll
    for (int nt = 0; nt < 4; nt++)
#pragma unroll
      for (int r = 0; r < 4; r++) {
        float y = acc[mt][nt][r] + biasv[nt];
        float z = fmaxf(a1v[nt] * y + c1v[nt], 0.0f);
        part[r] += z * w2v[nt];
      }
#pragma unroll
    for (int r = 0; r < 4; r++) {
      float p = part[r];
      p += __shfl_xor(p, 1); p += __shfl_xor(p, 2);
      p += __shfl_xor(p, 4); p += __shfl_xor(p, 8);
      part[r] = p + b2v;
    }
    if (l15 == 0) {
      int q = qt * 16 + w * 4 + mt;
      int P = ((b_ * 256 + q) * 128) + st * 16 + quad * 4;
      f32x4 o;
#pragma unroll
      for (int r = 0; r < 4; r++) { o[r] = part[r]; ls += part[r]; ls2 += part[r] * part[r]; }
      *(f32x4*)(a.y2 + P) = o;
    }
  }
  if (l15 == 0) { rs[t >> 4] = ls; rs2[t >> 4] = ls2; }
  __syncthreads();
  if (t == 0) {
    float s = 0, s2 = 0;
#pragma unroll
    for (int i = 0; i < 16; i++) { s += rs[i]; s2 += rs2[i]; }
    atomicAdd(&a.ws2f[(bi & 7) * 2], s);       // 64 adds/address
    atomicAdd(&a.ws2f[(bi & 7) * 2 + 1], s2);
  }
}

// ---------------------------------------------------------------------------
// D4: BN2 finalize (redundant, 16 floats) + out. 128 blocks, 4 floats/thread.
// ---------------------------------------------------------------------------
__global__ __launch_bounds__(256) void k_out(Args a)
{
  int t = threadIdx.x;
  float s = 0, s2 = 0;
#pragma unroll
  for (int c = 0; c < 8; c++) { s += a.ws2f[c * 2]; s2 += a.ws2f[c * 2 + 1]; }
  float mean = s * INV_N;
  float var = s2 * INV_N - mean * mean;
  float aa = a.g2[0] * rsqrtf(var + BN_EPS);
  float cc = a.bt2[0] - mean * aa;
  int i = (blockIdx.x * 256 + t) * 4;     // 128*256*4 = 131072 exactly
  f32x4 v = *(const f32x4*)(a.y2 + i);
  f32x4 o;
#pragma unroll
  for (int r = 0; r < 4; r++) o[r] = fmaxf(aa * v[r] + cc, 0.0f);
  *(f32x4*)(a.out + i) = o;
}

extern "C" void kernel_launch(void* const* d_in, const int* in_sizes, int n_in,
                              void* d_out, int out_size, void* d_ws, size_t ws_size,
                              hipStream_t stream)
{
  float* ws = (float*)d_ws;
  Args a;
  a.Sf  = (const float*)d_in[0];   // support [4,128,256]
  a.Qf  = (const float*)d_in[1];   // query   [4,256,256]
  a.W0  = (const float*)d_in[2];   // [256,512]
  a.b0  = (const float*)d_in[3];
  a.g0  = (const float*)d_in[4];
  a.bt0 = (const float*)d_in[5];
  a.W1  = (const float*)d_in[6];   // [64,256]
  a.b1  = (const float*)d_in[7];
  a.g1  = (const float*)d_in[8];
  a.bt1 = (const float*)d_in[9];
  a.W2  = (const float*)d_in[10];  // [1,64]
  a.b2  = (const float*)d_in[11];
  a.g2  = (const float*)d_in[12];
  a.bt2 = (const float*)d_in[13];

  a.Aq   = ws;                 // 262144 f
  a.As   = ws + 262144;        // 131072 f
  a.y2   = ws + 393216;        // 131072 f
  a.ws0s = ws + 524288;        // 96*512 = 49152 f (BN0 partial slots, fully overwritten)
  a.ws1f = ws + 573440;        // 1024 f (spread atomic accum, zeroed by D1 blk96)
  a.ws2f = ws + 574464;        // 16 f   (spread atomic accum, zeroed by D1 blk96)
  a.out  = (float*)d_out;      // total ws use ~2.3 MB

  k_g0 <<<97, 256, 0, stream>>>(a);
  k_m1 <<<512, 256, 0, stream>>>(a);
  k_m2 <<<512, 256, 0, stream>>>(a);
  k_out<<<128, 256, 0, stream>>>(a);
}